// Round 1
// baseline (278.442 us; speedup 1.0000x reference)
//
#include <hip/hip_runtime.h>

// FlowNetC correlation, B=16 C=256 H=48 W=64, 21x21 displacements (stride 2, +/-20).
// out[b, i*21+j, h, w] = sum_c in1[b,c,h,w] * in2[b,c,h+2i-20,w+2j-20]  (zero OOB)
//
// Strategy: f16 dot2 (v_dot2_f32_f16) with f32 accumulate. Block = (b,h) row,
// 7 waves x 3 rounds cover the 21 oy values. Per-lane register tile: 21 ox x 4 w
// (w parity-split, stride 2) so acc[o][i] += dot2(a[i], win[o+i]) -- 84 dot2 per
// 7 LDS b128 reads. 4-way c-split across lanes, reduced with shfl_xor at the end.

#define NB 16
#define NC 256
#define NH 48
#define NW 64
#define HW (NH * NW)
#define CHW (NC * NH * NW)
#define ND 21
#define NDISP (ND * ND)

typedef __fp16 half2v __attribute__((ext_vector_type(2)));

#if defined(__has_builtin)
#if __has_builtin(__builtin_amdgcn_fdot2)
#define HAVE_FDOT2 1
#endif
#endif

__device__ __forceinline__ float fdot2f(half2v a, half2v b, float c) {
#ifdef HAVE_FDOT2
    return __builtin_amdgcn_fdot2(a, b, c, false);
#else
    return c + (float)a.x * (float)b.x + (float)a.y * (float)b.y;
#endif
}

__device__ __forceinline__ unsigned pk2(float lo, float hi) {
    half2v h = __builtin_amdgcn_cvt_pkrtz(lo, hi);
    return __builtin_bit_cast(unsigned, h);
}
__device__ __forceinline__ half2v uph(unsigned u) {
    return __builtin_bit_cast(half2v, u);
}

// LDS layout (uint = packed f16x2 of channel pair (2*c2, 2*c2+1)):
//   in1_s[c2][p][k1] : [16][2][36], w = p + 2*k1, k1 in [0,32)
//   in2_s[wv][c2][p][kp] : [7][16][2][52], col = p + 2*(kp-10); valid kp [10,42),
//   aprons stay zero (zeroed once) -> ox clipping handled for free.
// Strides 36/52 give distinct bank starts for all 8 (ch,p) groups (conflict-free b128).
#define IN1_P 36
#define IN1_C2 (2 * IN1_P)     // 72
#define IN1_ELE (16 * IN1_C2)  // 1152
#define IN2_P 52
#define IN2_C2 (2 * IN2_P)     // 104
#define IN2_WV (16 * IN2_C2)   // 1664
#define LDS_ELE (IN1_ELE + 7 * IN2_WV)  // 12800 words = 50 KiB

__global__ __launch_bounds__(448, 4)
void corr_kernel(const float* __restrict__ in1, const float* __restrict__ in2,
                 float* __restrict__ out) {
    __shared__ __align__(16) unsigned lds[LDS_ELE];
    unsigned* in1_s = lds;
    unsigned* in2_s = lds + IN1_ELE;

    const int t = threadIdx.x;
    const int lane = t & 63;
    const int wid = t >> 6;          // 0..6
    const int tw = lane & 7;         // w-tile index
    const int p = (lane >> 3) & 1;   // w parity
    const int ch = lane >> 4;        // c-split group 0..3

    // XCD-chunked swizzle: each XCD gets 96 consecutive (b,h) blocks -> in2 row
    // sliding window stays hot in that XCD's L2.
    const int bx = blockIdx.x;
    const int L = (bx & 7) * 96 + (bx >> 3);
    const int b = L / NH;
    const int h = L % NH;

    // zero LDS once: establishes the permanent zero aprons in in2_s
    for (int i = t; i < LDS_ELE; i += 448) lds[i] = 0u;

    const float* in1_row = in1 + (size_t)b * CHW + (size_t)h * NW;

    #pragma unroll 1
    for (int r = 0; r < 3; ++r) {
        const int oyi = r * 7 + wid;                    // 0..20
        const int row = h + 2 * oyi - 20;               // in2 source row
        const bool valid = (unsigned)row < (unsigned)NH;

        float acc[21][4];
        #pragma unroll
        for (int o = 0; o < 21; ++o) {
            #pragma unroll
            for (int i = 0; i < 4; ++i) acc[o][i] = 0.f;
        }

        #pragma unroll 1
        for (int cb = 0; cb < 8; ++cb) {   // 8 chunks x 32 channels
            __syncthreads();               // prev chunk's compute done
            // ---- stage in1 chunk (block-shared, threads 0..255) ----
            if (t < 256) {
                const int c2l = t >> 4, col4 = t & 15;
                const float* s0 = in1_row + (size_t)(cb * 32 + 2 * c2l) * HW;
                const float4 u0 = ((const float4*)s0)[col4];
                const float4 u1 = ((const float4*)(s0 + HW))[col4];
                *(uint2*)&in1_s[c2l * IN1_C2 + 0 * IN1_P + 2 * col4] =
                    make_uint2(pk2(u0.x, u1.x), pk2(u0.z, u1.z));
                *(uint2*)&in1_s[c2l * IN1_C2 + 1 * IN1_P + 2 * col4] =
                    make_uint2(pk2(u0.y, u1.y), pk2(u0.w, u1.w));
            }
            // ---- stage in2 chunk for this wave's oy row ----
            if (valid) {
                const float* in2_row =
                    in2 + (size_t)b * CHW + (ptrdiff_t)row * NW;
                #pragma unroll
                for (int it = 0; it < 4; ++it) {
                    const int c2l = (lane >> 4) + it * 4, col4 = lane & 15;
                    const float* s0 = in2_row + (size_t)(cb * 32 + 2 * c2l) * HW;
                    const float4 u0 = ((const float4*)s0)[col4];
                    const float4 u1 = ((const float4*)(s0 + HW))[col4];
                    unsigned* dst = &in2_s[wid * IN2_WV + c2l * IN2_C2];
                    *(uint2*)&dst[0 * IN2_P + 2 * col4 + 10] =
                        make_uint2(pk2(u0.x, u1.x), pk2(u0.z, u1.z));
                    *(uint2*)&dst[1 * IN2_P + 2 * col4 + 10] =
                        make_uint2(pk2(u0.y, u1.y), pk2(u0.w, u1.w));
                }
            }
            __syncthreads();               // staging visible
            // ---- compute: 4 c2 iterations, 84 dot2 each ----
            if (valid) {
                #pragma unroll
                for (int u = 0; u < 4; ++u) {
                    const int c2l = ch + 4 * u;
                    const uint4 av =
                        *(const uint4*)&in1_s[c2l * IN1_C2 + p * IN1_P + 4 * tw];
                    const unsigned* wb =
                        &in2_s[wid * IN2_WV + c2l * IN2_C2 + p * IN2_P + 4 * tw];
                    const uint4 q0 = *(const uint4*)(wb + 0);
                    const uint4 q1 = *(const uint4*)(wb + 4);
                    const uint4 q2 = *(const uint4*)(wb + 8);
                    const uint4 q3 = *(const uint4*)(wb + 12);
                    const uint4 q4 = *(const uint4*)(wb + 16);
                    const uint4 q5 = *(const uint4*)(wb + 20);
                    const half2v a0 = uph(av.x), a1 = uph(av.y);
                    const half2v a2 = uph(av.z), a3 = uph(av.w);
                    const half2v win[24] = {
                        uph(q0.x), uph(q0.y), uph(q0.z), uph(q0.w),
                        uph(q1.x), uph(q1.y), uph(q1.z), uph(q1.w),
                        uph(q2.x), uph(q2.y), uph(q2.z), uph(q2.w),
                        uph(q3.x), uph(q3.y), uph(q3.z), uph(q3.w),
                        uph(q4.x), uph(q4.y), uph(q4.z), uph(q4.w),
                        uph(q5.x), uph(q5.y), uph(q5.z), uph(q5.w)};
                    #pragma unroll
                    for (int o = 0; o < 21; ++o) {
                        acc[o][0] = fdot2f(a0, win[o + 0], acc[o][0]);
                        acc[o][1] = fdot2f(a1, win[o + 1], acc[o][1]);
                        acc[o][2] = fdot2f(a2, win[o + 2], acc[o][2]);
                        acc[o][3] = fdot2f(a3, win[o + 3], acc[o][3]);
                    }
                }
            }
        }

        // ---- output: reduce the 4-way c-split, then store ----
        float* orow = out + ((size_t)(b * NDISP + oyi * ND) * NH + h) * NW;
        if (valid) {
            #pragma unroll
            for (int o = 0; o < 21; ++o) {
                #pragma unroll
                for (int i = 0; i < 4; ++i) {
                    float v = acc[o][i];
                    v += __shfl_xor(v, 16);
                    v += __shfl_xor(v, 32);
                    acc[o][i] = v;
                }
            }
            // distribute stores over ch groups: ox ranges {0..5},{6..10},{11..15},{16..20}
            const int os = (ch == 0) ? 0 : (1 + 5 * ch);
            const int oe = os + ((ch == 0) ? 6 : 5);
            #pragma unroll
            for (int o = 0; o < 21; ++o) {
                if (o >= os && o < oe) {
                    #pragma unroll
                    for (int i = 0; i < 4; ++i)
                        orow[(size_t)o * HW + (p + 8 * tw + 2 * i)] = acc[o][i];
                }
            }
        } else {
            // OOB oy row: whole 21x64 slab is zero
            #pragma unroll
            for (int o = 0; o < 21; ++o) orow[(size_t)o * HW + lane] = 0.f;
        }
    }
}

extern "C" void kernel_launch(void* const* d_in, const int* in_sizes, int n_in,
                              void* d_out, int out_size, void* d_ws, size_t ws_size,
                              hipStream_t stream) {
    const float* in1 = (const float*)d_in[0];
    const float* in2 = (const float*)d_in[1];
    float* out = (float*)d_out;
    corr_kernel<<<dim3(NB * NH), dim3(448), 0, stream>>>(in1, in2, out);
}

// Round 2
// 138.076 us; speedup vs baseline: 2.0166x; 2.0166x over previous
//
#include <hip/hip_runtime.h>

// FlowNetC correlation, B=16 C=256 H=48 W=64, 21x21 displacements (stride 2, +/-20).
// out[b, i*21+j, h, w] = sum_c in1[b,c,h,w] * in2[b,c,h+2i-20,w+2j-20]  (zero OOB)
//
// v2: barrier-free main loop. Full in1 row staged to LDS as f16x2 once (one
// __syncthreads); each wave owns a private in2 staging buffer and processes its
// oy list independently with software prefetch (global->reg issued before the
// compute that hides it). acc[11][4] per lane (2-way ox split x 2-way c split)
// -- fits registers, no spill (round-1 failure mode: acc[21][4] spilled at
// VGPR=64). Lane bits (tw:3, oh:1, p:1, chalf:1) chosen so every 16-lane LDS
// phase is bank-perfect.

#define NB 16
#define NC 256
#define NH 48
#define NW 64
#define HW (NH * NW)
#define CHW (NC * NH * NW)
#define ND 21
#define NDISP (ND * ND)

#define NCB 16                       // channel chunks, 16 channels (8 c2) each
#define IN1_P 36
#define IN1_C2 (2 * IN1_P)           // 72
#define IN1_WORDS (128 * IN1_C2)     // 9216
#define IN2_P 52
#define IN2_C2 (2 * IN2_P)           // 104
#define IN2_WAVE (8 * IN2_C2)        // 832
#define LDS_WORDS (IN1_WORDS + 4 * IN2_WAVE)  // 12544 words = 50176 B -> 3 blocks/CU

typedef __fp16 half2v __attribute__((ext_vector_type(2)));

#if defined(__has_builtin)
#if __has_builtin(__builtin_amdgcn_fdot2)
#define HAVE_FDOT2 1
#endif
#endif

__device__ __forceinline__ float fdot2f(half2v a, half2v b, float c) {
#ifdef HAVE_FDOT2
    return __builtin_amdgcn_fdot2(a, b, c, false);
#else
    return c + (float)a.x * (float)b.x + (float)a.y * (float)b.y;
#endif
}
__device__ __forceinline__ unsigned pk2(float lo, float hi) {
    half2v h = __builtin_amdgcn_cvt_pkrtz(lo, hi);
    return __builtin_bit_cast(unsigned, h);
}
__device__ __forceinline__ half2v uph(unsigned u) {
    return __builtin_bit_cast(half2v, u);
}

// LDS word layouts (word = packed f16x2 of channel pair):
//   in1_s[c2 128][p 2][36] : word k1 -> w = p + 2*k1 (k1 in [0,32), 4 pad words)
//   in2w [c2 8][p 2][52]   : word kp -> col = p + 2*(kp-10); valid kp [10,42),
//                            aprons zeroed once -> ox edge clipping is free.

__global__ __launch_bounds__(256, 3)
void corr_kernel(const float* __restrict__ in1, const float* __restrict__ in2,
                 float* __restrict__ out) {
    __shared__ __align__(16) unsigned lds[LDS_WORDS];
    unsigned* in1_s = lds;

    const int t = threadIdx.x;
    const int lane = t & 63;
    const int wid = t >> 6;              // 0..3
    const int tw = lane & 7;             // w-tile: w = p + 8*tw + 2*i
    const int oh = (lane >> 3) & 1;      // ox half: o_global = 10*oh + ol
    const int p = (lane >> 4) & 1;       // w parity
    const int chalf = (lane >> 5) & 1;   // c split (partner = lane ^ 32)

    unsigned* in2w = lds + IN1_WORDS + wid * IN2_WAVE;

    // XCD-chunked swizzle (768 % 8 == 0 -> bijective)
    const int bx = blockIdx.x;
    const int L = (bx & 7) * 96 + (bx >> 3);
    const int b = L / NH;
    const int h = L % NH;

    const float* in1_row = in1 + (size_t)b * CHW + (size_t)h * NW;

    // zero own wave's in2 buffer once (permanent zero aprons)
    for (int i = lane; i < IN2_WAVE; i += 64) in2w[i] = 0u;

    // stage the FULL in1 row (256 ch x 64 w) as packed f16x2, parity-split
    #pragma unroll 1
    for (int j = 0; j < 8; ++j) {
        const int task = t + 256 * j;    // 0..2047 = c2(128) x col4(16)
        const int c2 = task >> 4;
        const int c4 = task & 15;
        const float4 u0 = ((const float4*)(in1_row + (size_t)(2 * c2) * HW))[c4];
        const float4 u1 = ((const float4*)(in1_row + (size_t)(2 * c2 + 1) * HW))[c4];
        unsigned* d0 = &in1_s[c2 * IN1_C2 + 2 * c4];
        *(uint2*)&d0[0]     = make_uint2(pk2(u0.x, u1.x), pk2(u0.z, u1.z));
        *(uint2*)&d0[IN1_P] = make_uint2(pk2(u0.y, u1.y), pk2(u0.w, u1.w));
    }
    __syncthreads();   // the only barrier: in1_s is read-only from here on

    const int q = lane >> 4;       // staging sub-index 0..3
    const int col4 = lane & 15;

    #pragma unroll 1
    for (int s = 0; s < 6; ++s) {
        const int oyi = wid + 4 * s;          // each oy in [0,21) exactly once
        if (oyi >= ND) break;                 // wave-uniform
        const int row = h + 2 * oyi - 20;
        float* orow = out + ((size_t)(b * NDISP + oyi * ND) * NH + h) * NW;
        if ((unsigned)row >= (unsigned)NH) {  // OOB oy row: zero slab
            #pragma unroll
            for (int o = 0; o < ND; ++o) orow[(size_t)o * HW + lane] = 0.f;
            continue;
        }
        const float* in2_row = in2 + (size_t)b * CHW + (size_t)row * NW;

        float acc[11][4];
        #pragma unroll
        for (int ol = 0; ol < 11; ++ol) {
            #pragma unroll
            for (int i = 0; i < 4; ++i) acc[ol][i] = 0.f;
        }

        // prologue: issue chunk-0 global loads
        float4 pre[4];
        {
            const float* s0 = in2_row + (size_t)(2 * q) * HW;
            const float* s1 = in2_row + (size_t)(2 * (q + 4)) * HW;
            pre[0] = ((const float4*)s0)[col4];
            pre[1] = ((const float4*)(s0 + HW))[col4];
            pre[2] = ((const float4*)s1)[col4];
            pre[3] = ((const float4*)(s1 + HW))[col4];
        }

        #pragma unroll 1
        for (int cb = 0; cb < NCB; ++cb) {
            // pack + LDS-write chunk cb (implicit vmcnt wait on pre)
            {
                unsigned* da = &in2w[q * IN2_C2 + 2 * col4 + 10];
                unsigned* db = &in2w[(q + 4) * IN2_C2 + 2 * col4 + 10];
                *(uint2*)&da[0]     = make_uint2(pk2(pre[0].x, pre[1].x), pk2(pre[0].z, pre[1].z));
                *(uint2*)&da[IN2_P] = make_uint2(pk2(pre[0].y, pre[1].y), pk2(pre[0].w, pre[1].w));
                *(uint2*)&db[0]     = make_uint2(pk2(pre[2].x, pre[3].x), pk2(pre[2].z, pre[3].z));
                *(uint2*)&db[IN2_P] = make_uint2(pk2(pre[2].y, pre[3].y), pk2(pre[2].w, pre[3].w));
            }
            // prefetch chunk cb+1 (hides under compute below)
            if (cb + 1 < NCB) {
                const float* srcn = in2_row + (size_t)((cb + 1) * 16) * HW;
                const float* s0 = srcn + (size_t)(2 * q) * HW;
                const float* s1 = srcn + (size_t)(2 * (q + 4)) * HW;
                pre[0] = ((const float4*)s0)[col4];
                pre[1] = ((const float4*)(s0 + HW))[col4];
                pre[2] = ((const float4*)s1)[col4];
                pre[3] = ((const float4*)(s1 + HW))[col4];
            }
            // compute chunk cb: 4 c2 per lane, 176 dot2
            #pragma unroll
            for (int u = 0; u < 4; ++u) {
                const int c2l = 2 * u + chalf;
                const uint4 av =
                    *(const uint4*)&in1_s[(cb * 8 + c2l) * IN1_C2 + p * IN1_P + 4 * tw];
                const unsigned* wb =
                    &in2w[c2l * IN2_C2 + p * IN2_P + 4 * tw + 10 * oh];
                const uint2 w0 = *(const uint2*)(wb + 0);
                const uint2 w1 = *(const uint2*)(wb + 2);
                const uint2 w2 = *(const uint2*)(wb + 4);
                const uint2 w3 = *(const uint2*)(wb + 6);
                const uint2 w4 = *(const uint2*)(wb + 8);
                const uint2 w5 = *(const uint2*)(wb + 10);
                const uint2 w6 = *(const uint2*)(wb + 12);
                const half2v a0 = uph(av.x), a1 = uph(av.y);
                const half2v a2 = uph(av.z), a3 = uph(av.w);
                const half2v win[14] = {uph(w0.x), uph(w0.y), uph(w1.x), uph(w1.y),
                                        uph(w2.x), uph(w2.y), uph(w3.x), uph(w3.y),
                                        uph(w4.x), uph(w4.y), uph(w5.x), uph(w5.y),
                                        uph(w6.x), uph(w6.y)};
                #pragma unroll
                for (int ol = 0; ol < 11; ++ol) {
                    acc[ol][0] = fdot2f(a0, win[ol + 0], acc[ol][0]);
                    acc[ol][1] = fdot2f(a1, win[ol + 1], acc[ol][1]);
                    acc[ol][2] = fdot2f(a2, win[ol + 2], acc[ol][2]);
                    acc[ol][3] = fdot2f(a3, win[ol + 3], acc[ol][3]);
                }
            }
        }

        // reduce the 2-way c split (lane bit 5), then store
        #pragma unroll
        for (int ol = 0; ol < 11; ++ol) {
            #pragma unroll
            for (int i = 0; i < 4; ++i) {
                float v = acc[ol][i];
                v += __shfl_xor(v, 32);
                acc[ol][i] = v;
            }
        }
        if (chalf == 0) {
            #pragma unroll
            for (int ol = 0; ol < 11; ++ol) {
                if (oh == 1 && ol == 0) continue;   // o=10 duplicated across halves
                const int og = 10 * oh + ol;
                #pragma unroll
                for (int i = 0; i < 4; ++i)
                    orow[(size_t)og * HW + (p + 8 * tw + 2 * i)] = acc[ol][i];
            }
        }
    }
}

extern "C" void kernel_launch(void* const* d_in, const int* in_sizes, int n_in,
                              void* d_out, int out_size, void* d_ws, size_t ws_size,
                              hipStream_t stream) {
    const float* in1 = (const float*)d_in[0];
    const float* in2 = (const float*)d_in[1];
    float* out = (float*)d_out;
    corr_kernel<<<dim3(NB * NH), dim3(256), 0, stream>>>(in1, in2, out);
}

// Round 3
// 135.094 us; speedup vs baseline: 2.0611x; 1.0221x over previous
//
#include <hip/hip_runtime.h>

// FlowNetC correlation, B=16 C=256 H=48 W=64, 21x21 displacements (stride 2, +/-20).
// out[b, i*21+j, h, w] = sum_c in1[b,c,h,w] * in2[b,c,h+2i-20,w+2j-20]  (zero OOB)
//
// v3 (scheduling fixes over v2; math identical):
//  - Batched operand loads: all 4 u-iterations' LDS reads (4x b128 + 28x b64)
//    issued before the 176-dot2 block -> ~130 live VGPRs, reads pipeline instead
//    of 4 serial lgkmcnt stalls (v2: VGPR=68, per-wave duty ~40%).
//  - Wave-balanced oy: valid range [lo,hi] dealt round-robin with per-block
//    rotation (wid+h)&3 so the ceil-share rotates across SIMDs (v2: wid0/SIMD0
//    always longest -> occupancy 23.6% vs 37.5% ceiling).

#define NB 16
#define NC 256
#define NH 48
#define NW 64
#define HW (NH * NW)
#define CHW (NC * NH * NW)
#define ND 21
#define NDISP (ND * ND)

#define NCB 16                       // channel chunks, 16 channels (8 c2) each
#define IN1_P 36
#define IN1_C2 (2 * IN1_P)           // 72
#define IN1_WORDS (128 * IN1_C2)     // 9216
#define IN2_P 52
#define IN2_C2 (2 * IN2_P)           // 104
#define IN2_WAVE (8 * IN2_C2)        // 832
#define LDS_WORDS (IN1_WORDS + 4 * IN2_WAVE)  // 12544 words = 50176 B -> 3 blocks/CU

typedef __fp16 half2v __attribute__((ext_vector_type(2)));

#if defined(__has_builtin)
#if __has_builtin(__builtin_amdgcn_fdot2)
#define HAVE_FDOT2 1
#endif
#endif

__device__ __forceinline__ float fdot2f(half2v a, half2v b, float c) {
#ifdef HAVE_FDOT2
    return __builtin_amdgcn_fdot2(a, b, c, false);
#else
    return c + (float)a.x * (float)b.x + (float)a.y * (float)b.y;
#endif
}
__device__ __forceinline__ unsigned pk2(float lo, float hi) {
    half2v h = __builtin_amdgcn_cvt_pkrtz(lo, hi);
    return __builtin_bit_cast(unsigned, h);
}
__device__ __forceinline__ half2v uph(unsigned u) {
    return __builtin_bit_cast(half2v, u);
}

// LDS word layouts (word = packed f16x2 of channel pair):
//   in1_s[c2 128][p 2][36] : word k1 -> w = p + 2*k1 (k1 in [0,32), 4 pad words)
//   in2w [c2 8][p 2][52]   : word kp -> col = p + 2*(kp-10); valid kp [10,42),
//                            aprons zeroed once -> ox edge clipping is free.

// window word m (= ol+i) from the batched uint2 array, m in [0,14) compile-time
#define WW(u, m) uph(((m) & 1) ? wn[u][(m) >> 1].y : wn[u][(m) >> 1].x)

__global__ __launch_bounds__(256, 3)
void corr_kernel(const float* __restrict__ in1, const float* __restrict__ in2,
                 float* __restrict__ out) {
    __shared__ __align__(16) unsigned lds[LDS_WORDS];
    unsigned* in1_s = lds;

    const int t = threadIdx.x;
    const int lane = t & 63;
    const int wid = t >> 6;              // 0..3
    const int tw = lane & 7;             // w-tile: w = p + 8*tw + 2*i
    const int oh = (lane >> 3) & 1;      // ox half: o_global = 10*oh + ol
    const int p = (lane >> 4) & 1;       // w parity
    const int chalf = (lane >> 5) & 1;   // c split (partner = lane ^ 32)

    unsigned* in2w = lds + IN1_WORDS + wid * IN2_WAVE;

    // XCD-chunked swizzle (768 % 8 == 0 -> bijective)
    const int bx = blockIdx.x;
    const int L = (bx & 7) * 96 + (bx >> 3);
    const int b = L / NH;
    const int h = L % NH;

    const float* in1_row = in1 + (size_t)b * CHW + (size_t)h * NW;

    // zero own wave's in2 buffer once (permanent zero aprons)
    for (int i = lane; i < IN2_WAVE; i += 64) in2w[i] = 0u;

    // stage the FULL in1 row (256 ch x 64 w) as packed f16x2, parity-split
    #pragma unroll 1
    for (int j = 0; j < 8; ++j) {
        const int task = t + 256 * j;    // 0..2047 = c2(128) x col4(16)
        const int c2 = task >> 4;
        const int c4 = task & 15;
        const float4 u0 = ((const float4*)(in1_row + (size_t)(2 * c2) * HW))[c4];
        const float4 u1 = ((const float4*)(in1_row + (size_t)(2 * c2 + 1) * HW))[c4];
        unsigned* d0 = &in1_s[c2 * IN1_C2 + 2 * c4];
        *(uint2*)&d0[0]     = make_uint2(pk2(u0.x, u1.x), pk2(u0.z, u1.z));
        *(uint2*)&d0[IN1_P] = make_uint2(pk2(u0.y, u1.y), pk2(u0.w, u1.w));
    }
    __syncthreads();   // the only barrier: in1_s is read-only from here on

    const int q = lane >> 4;       // staging sub-index 0..3
    const int col4 = lane & 15;

    // valid oy range for this h (contiguous), dealt round-robin across waves
    const int lo = (h >= 20) ? 0 : ((21 - h) >> 1);
    const int hi = min(20, (67 - h) >> 1);
    const int nv = hi - lo + 1;          // 11..21
    const int rot = (wid + h) & 3;       // rotate the ceil-share across SIMDs

    // OOB oy rows: zero slabs, same round-robin deal
    #pragma unroll 1
    for (int oy = rot; oy < ND; oy += 4) {
        if (oy >= lo && oy <= hi) continue;
        float* orow = out + ((size_t)(b * NDISP + oy * ND) * NH + h) * NW;
        #pragma unroll
        for (int o = 0; o < ND; ++o) orow[(size_t)o * HW + lane] = 0.f;
    }

    #pragma unroll 1
    for (int k = rot; k < nv; k += 4) {
        const int oyi = lo + k;
        const int row = h + 2 * oyi - 20;
        float* orow = out + ((size_t)(b * NDISP + oyi * ND) * NH + h) * NW;
        const float* in2_row = in2 + (size_t)b * CHW + (size_t)row * NW;

        float acc[11][4];
        #pragma unroll
        for (int ol = 0; ol < 11; ++ol) {
            #pragma unroll
            for (int i = 0; i < 4; ++i) acc[ol][i] = 0.f;
        }

        // prologue: issue chunk-0 global loads
        float4 pre[4];
        {
            const float* s0 = in2_row + (size_t)(2 * q) * HW;
            const float* s1 = in2_row + (size_t)(2 * (q + 4)) * HW;
            pre[0] = ((const float4*)s0)[col4];
            pre[1] = ((const float4*)(s0 + HW))[col4];
            pre[2] = ((const float4*)s1)[col4];
            pre[3] = ((const float4*)(s1 + HW))[col4];
        }

        #pragma unroll 1
        for (int cb = 0; cb < NCB; ++cb) {
            // pack + LDS-write chunk cb (implicit vmcnt wait on pre)
            {
                unsigned* da = &in2w[q * IN2_C2 + 2 * col4 + 10];
                unsigned* db = &in2w[(q + 4) * IN2_C2 + 2 * col4 + 10];
                *(uint2*)&da[0]     = make_uint2(pk2(pre[0].x, pre[1].x), pk2(pre[0].z, pre[1].z));
                *(uint2*)&da[IN2_P] = make_uint2(pk2(pre[0].y, pre[1].y), pk2(pre[0].w, pre[1].w));
                *(uint2*)&db[0]     = make_uint2(pk2(pre[2].x, pre[3].x), pk2(pre[2].z, pre[3].z));
                *(uint2*)&db[IN2_P] = make_uint2(pk2(pre[2].y, pre[3].y), pk2(pre[2].w, pre[3].w));
            }
            // prefetch chunk cb+1 (hides under compute below)
            if (cb + 1 < NCB) {
                const float* srcn = in2_row + (size_t)((cb + 1) * 16) * HW;
                const float* s0 = srcn + (size_t)(2 * q) * HW;
                const float* s1 = srcn + (size_t)(2 * (q + 4)) * HW;
                pre[0] = ((const float4*)s0)[col4];
                pre[1] = ((const float4*)(s0 + HW))[col4];
                pre[2] = ((const float4*)s1)[col4];
                pre[3] = ((const float4*)(s1 + HW))[col4];
            }
            // batched LDS reads for ALL 4 u-iterations (pipelined, no per-u stall)
            uint4 av[4];
            uint2 wn[4][7];
            {
                const unsigned* base1 =
                    &in1_s[(cb * 8 + chalf) * IN1_C2 + p * IN1_P + 4 * tw];
                const unsigned* base2 =
                    &in2w[chalf * IN2_C2 + p * IN2_P + 4 * tw + 10 * oh];
                #pragma unroll
                for (int u = 0; u < 4; ++u) {
                    av[u] = *(const uint4*)(base1 + (size_t)(2 * u) * IN1_C2);
                    #pragma unroll
                    for (int j = 0; j < 7; ++j)
                        wn[u][j] = *(const uint2*)(base2 + (size_t)(2 * u) * IN2_C2 + 2 * j);
                }
            }
            // compute chunk cb: 176 dot2
            #pragma unroll
            for (int u = 0; u < 4; ++u) {
                const half2v a0 = uph(av[u].x), a1 = uph(av[u].y);
                const half2v a2 = uph(av[u].z), a3 = uph(av[u].w);
                #pragma unroll
                for (int ol = 0; ol < 11; ++ol) {
                    acc[ol][0] = fdot2f(a0, WW(u, ol + 0), acc[ol][0]);
                    acc[ol][1] = fdot2f(a1, WW(u, ol + 1), acc[ol][1]);
                    acc[ol][2] = fdot2f(a2, WW(u, ol + 2), acc[ol][2]);
                    acc[ol][3] = fdot2f(a3, WW(u, ol + 3), acc[ol][3]);
                }
            }
        }

        // reduce the 2-way c split (lane bit 5), then store
        #pragma unroll
        for (int ol = 0; ol < 11; ++ol) {
            #pragma unroll
            for (int i = 0; i < 4; ++i) {
                float v = acc[ol][i];
                v += __shfl_xor(v, 32);
                acc[ol][i] = v;
            }
        }
        if (chalf == 0) {
            #pragma unroll
            for (int ol = 0; ol < 11; ++ol) {
                if (oh == 1 && ol == 0) continue;   // o=10 duplicated across halves
                const int og = 10 * oh + ol;
                #pragma unroll
                for (int i = 0; i < 4; ++i)
                    orow[(size_t)og * HW + (p + 8 * tw + 2 * i)] = acc[ol][i];
            }
        }
    }
}

extern "C" void kernel_launch(void* const* d_in, const int* in_sizes, int n_in,
                              void* d_out, int out_size, void* d_ws, size_t ws_size,
                              hipStream_t stream) {
    const float* in1 = (const float*)d_in[0];
    const float* in2 = (const float*)d_in[1];
    float* out = (float*)d_out;
    corr_kernel<<<dim3(NB * NH), dim3(256), 0, stream>>>(in1, in2, out);
}